// Round 10
// baseline (11035.956 us; speedup 1.0000x reference)
//
#include <hip/hip_runtime.h>
#include <math.h>

// KimiK2 MoE gate. Round 10: round-9 semantics (bit-exact, ties->higher),
// software-pipelined inner loop: x via per-lane global dwordx4 (vmcnt queue),
// w via padded-LDS ds_read_b128 (lgkm queue), both prefetched one q-group
// ahead into named A/B register sets. Occupancy grid-capped at 2 waves/SIMD,
// so all hiding is ILP. Output: [T*8 indices as float][T*8 weights].

#define HH 7168
#define EE 256
#define BMT 32
#define BK 32
#define NTH 256
#define WROW 36

typedef float v4f __attribute__((ext_vector_type(4)));

struct SMem {
    union {
        float wl[EE][WROW];     // 36 KB padded w slice
        float logits[BMT][EE];  // 32 KB
    } u;
    float bias[EE];
};

__device__ __forceinline__ void load_w(v4f wreg[4], const char* wb, int q) {
    wreg[0] = *(const v4f*)(wb + q * 16);
    wreg[1] = *(const v4f*)(wb + 64 * WROW * 4 + q * 16);
    wreg[2] = *(const v4f*)(wb + 128 * WROW * 4 + q * 16);
    wreg[3] = *(const v4f*)(wb + 192 * WROW * 4 + q * 16);
}

__device__ __forceinline__ void load_x(v4f xreg[8], const char* xb,
                                       const unsigned voff[8], int boff) {
    #pragma unroll
    for (int t = 0; t < 8; ++t)
        xreg[t] = *(const v4f*)(xb + voff[t] + boff);
}

__device__ __forceinline__ void fma_block(float acc[8][4], const v4f xreg[8],
                                          const v4f wreg[4]) {
    #pragma unroll
    for (int t = 0; t < 8; ++t) {
        #pragma unroll
        for (int c = 0; c < 4; ++c) {   // k ascends within acc chain
            float xs = xreg[t][c];
            acc[t][0] = fmaf(xs, wreg[0][c], acc[t][0]);
            acc[t][1] = fmaf(xs, wreg[1][c], acc[t][1]);
            acc[t][2] = fmaf(xs, wreg[2][c], acc[t][2]);
            acc[t][3] = fmaf(xs, wreg[3][c], acc[t][3]);
        }
    }
}

__global__ __launch_bounds__(NTH, 2)
void moe_gate(const float* __restrict__ x, const float* __restrict__ w,
              const float* __restrict__ bias, float* __restrict__ out, int T) {
    __shared__ SMem sm;
    const int tid = threadIdx.x;
    const int bm = blockIdx.x * BMT;
    sm.bias[tid] = bias[tid];
    const int lane = tid & 63;
    const int wv = __builtin_amdgcn_readfirstlane(tid >> 6);

    // opaque zero (laneid>>6) to keep x addressing in the vector/vmcnt path
    unsigned lzero = (__builtin_amdgcn_mbcnt_hi(
        ~0u, __builtin_amdgcn_mbcnt_lo(~0u, 0u))) >> 6;

    // w staging: thread stages rows eg0+32p, cols kg*4..kg*4+3
    const int kg = tid & 7;
    const int eg0 = tid >> 3;
    const float* wg = w + (size_t)eg0 * HH + kg * 4;

    const char* xb = (const char*)(x + (size_t)(bm + wv * 8) * HH);
    unsigned voff[8];
    #pragma unroll
    for (int t = 0; t < 8; ++t) voff[t] = (unsigned)(t * HH * 4) + lzero;

    const char* wb = (const char*)&sm.u.wl[lane][0];

    float acc[8][4];
    #pragma unroll
    for (int t = 0; t < 8; ++t)
        #pragma unroll
        for (int j = 0; j < 4; ++j) acc[t][j] = 0.f;

    v4f sreg[8];
    #pragma unroll
    for (int p = 0; p < 8; ++p)
        sreg[p] = *(const v4f*)(wg + (size_t)p * 32 * HH);

    v4f wA[4], wB[4], xA[8], xB[8];
    load_x(xA, xb, voff, 0);   // q=0 of k0=0

    for (int k0 = 0; k0 < HH; k0 += BK) {
        __syncthreads();
        #pragma unroll
        for (int p = 0; p < 8; ++p)
            *(v4f*)&sm.u.wl[eg0 + 32 * p][kg * 4] = sreg[p];
        __syncthreads();
        if (k0 + BK < HH) {
            const float* wgk = wg + k0 + BK;
            #pragma unroll
            for (int p = 0; p < 8; ++p)
                sreg[p] = *(const v4f*)(wgk + (size_t)p * 32 * HH);
        }
        load_w(wA, wb, 0);
        #pragma unroll
        for (int qq = 0; qq < 4; ++qq) {
            const int q1 = qq * 2 + 1;
            // prefetch q1 into B
            load_w(wB, wb, q1);
            load_x(xB, xb, voff, k0 * 4 + q1 * 16);
            fma_block(acc, xA, wA);              // k = k0 + qq*8 .. +3
            if (q1 < 7) {
                load_w(wA, wb, q1 + 1);
                load_x(xA, xb, voff, k0 * 4 + (q1 + 1) * 16);
            } else if (k0 + BK < HH) {
                load_x(xA, xb, voff, (k0 + BK) * 4);  // next k0, q=0
            }
            fma_block(acc, xB, wB);              // k = k0 + qq*8+4 .. +7
        }
    }

    __syncthreads();
    #pragma unroll
    for (int t = 0; t < 8; ++t)
        #pragma unroll
        for (int j = 0; j < 4; ++j)
            sm.u.logits[wv * 8 + t][lane + 64 * j] = acc[t][j];
    __syncthreads();

    // ---- routing: round-7 verbatim (ties -> higher index) ----
    for (int tt = wv; tt < BMT; tt += 4) {
        const int gt = bm + tt;
        float4 lg = *(const float4*)&sm.u.logits[tt][lane * 4];
        float lgv[4] = {lg.x, lg.y, lg.z, lg.w};
        float s[4], sc[4], m[4];
        #pragma unroll
        for (int j = 0; j < 4; ++j) {
            float e = (float)exp(-(double)lgv[j]);
            float u = __fadd_rn(1.0f, e);
            s[j] = __fdiv_rn(1.0f, u);
            sc[j] = __fadd_rn(s[j], sm.bias[lane * 4 + j]);
        }
        float a1 = fmaxf(sc[0], sc[1]), a2 = fminf(sc[0], sc[1]);
        if (sc[2] > a1) { a2 = a1; a1 = sc[2]; } else a2 = fmaxf(a2, sc[2]);
        if (sc[3] > a1) { a2 = a1; a1 = sc[3]; } else a2 = fmaxf(a2, sc[3]);
        #pragma unroll
        for (int off = 1; off <= 4; off <<= 1) {
            float b1 = __shfl_xor(a1, off);
            float b2 = __shfl_xor(a2, off);
            float m1 = fmaxf(a1, b1);
            float m2 = fmaxf(fminf(a1, b1), (a1 >= b1) ? a2 : b2);
            a1 = m1; a2 = m2;
        }
        float gsc = __fadd_rn(a1, a2);
        float gsv[8];
        #pragma unroll
        for (int g = 0; g < 8; ++g) gsv[g] = __shfl(gsc, g * 8);
        int gm = lane >> 3;
        int rank = 0;
        #pragma unroll
        for (int hh = 0; hh < 8; ++hh)
            rank += (gsv[hh] > gsv[gm]) || (gsv[hh] == gsv[gm] && hh > gm);
        bool selg = rank < 4;
        #pragma unroll
        for (int j = 0; j < 4; ++j) m[j] = selg ? sc[j] : 0.0f;

        float selw = 0.f; int seli = 0;
        #pragma unroll
        for (int k = 0; k < 8; ++k) {
            float bv = m[0]; int bj = 0;
            #pragma unroll
            for (int j = 1; j < 4; ++j)
                if (m[j] >= bv) { bv = m[j]; bj = j; }
            float v = bv; int ii = lane * 4 + bj;
            #pragma unroll
            for (int off = 1; off < 64; off <<= 1) {
                float ov = __shfl_xor(v, off);
                int oi = __shfl_xor(ii, off);
                if (ov > v || (ov == v && oi > ii)) { v = ov; ii = oi; }
            }
            int oj = ii & 3, ol = ii >> 2;
            float cand = (oj == 0) ? s[0] : (oj == 1) ? s[1]
                       : (oj == 2) ? s[2] : s[3];
            float wgt = __shfl(cand, ol);
            if (lane == k) { seli = ii; selw = wgt; }
            if (lane == ol) {
                if (oj == 0) m[0] = -1e30f;
                else if (oj == 1) m[1] = -1e30f;
                else if (oj == 2) m[2] = -1e30f;
                else m[3] = -1e30f;
            }
        }
        float wk[8];
        #pragma unroll
        for (int k = 0; k < 8; ++k) wk[k] = __shfl(selw, k);
        float denom = __fadd_rn(
            __fadd_rn(__fadd_rn(wk[0], wk[1]), __fadd_rn(wk[2], wk[3])),
            __fadd_rn(__fadd_rn(wk[4], wk[5]), __fadd_rn(wk[6], wk[7])));
        denom = __fadd_rn(denom, 1e-20f);
        if (lane < 8) {
            out[(size_t)gt * 8 + lane] = (float)seli;
            out[(size_t)T * 8 + (size_t)gt * 8 + lane] =
                __fmul_rn(__fdiv_rn(selw, denom), 2.5f);
        }
    }
}

extern "C" void kernel_launch(void* const* d_in, const int* in_sizes, int n_in,
                              void* d_out, int out_size, void* d_ws, size_t ws_size,
                              hipStream_t stream) {
    const float* x    = (const float*)d_in[0];
    const float* w    = (const float*)d_in[1];
    const float* bias = (const float*)d_in[2];
    float* out = (float*)d_out;
    const int T = in_sizes[0] / HH; // 16384
    moe_gate<<<T / BMT, NTH, 0, stream>>>(x, w, bias, out, T);
}

// Round 11
// 882.525 us; speedup vs baseline: 12.5050x; 12.5050x over previous
//
#include <hip/hip_runtime.h>
#include <math.h>

// KimiK2 MoE gate. Round 11: all-DS operand path + async global_load_lds
// staging (double-buffered), w XOR-swizzled via pre-swizzled global source.
// Semantics bit-identical to round 7/9 (ties -> higher index).
// Output: [T*8 indices as float][T*8 weights].

#define HH 7168
#define EE 256
#define BMT 32
#define BK 32
#define NTH 256

typedef float v4f __attribute__((ext_vector_type(4)));

struct SMem {
    union {
        float wbuf[2][EE * BK];     // 64 KB (2 x 32 KB w slices)
        float logits[BMT][EE];      // 32 KB
    } u;
    float xbuf[2][BMT * BK];        // 8 KB
    float bias[EE];
};

__device__ __forceinline__ void gl16(const void* g, void* l) {
    __builtin_amdgcn_global_load_lds(
        (__attribute__((address_space(1))) const void*)g,
        (__attribute__((address_space(3))) void*)l, 16, 0, 0);
}

__global__ __launch_bounds__(NTH, 2)
void moe_gate(const float* __restrict__ x, const float* __restrict__ w,
              const float* __restrict__ bias, float* __restrict__ out, int T) {
    __shared__ SMem sm;
    const int tid = threadIdx.x;
    const int bm = blockIdx.x * BMT;
    sm.bias[tid] = bias[tid];
    const int lane = tid & 63;
    const int wv = __builtin_amdgcn_readfirstlane(tid >> 6);
    const int l3 = lane >> 3, l7 = lane & 7;

    // staging geometry: wave wv stages w rows [wv*64, wv*64+64), its 8 x rows
    const int cch = l7 ^ l3;  // pre-swizzled source chunk (row&7 == l3)
    const float* wsrc = w + (size_t)(wv * 64 + l3) * HH + cch * 4;
    const float* xsrc = x + (size_t)(bm + wv * 8 + l3) * HH + l7 * 4;
    float* const wdst0 = &sm.u.wbuf[0][wv * 64 * BK];
    float* const wdst1 = &sm.u.wbuf[1][wv * 64 * BK];
    float* const xdst0 = &sm.xbuf[0][wv * 8 * BK];
    float* const xdst1 = &sm.xbuf[1][wv * 8 * BK];

    float acc[8][4];
    #pragma unroll
    for (int t = 0; t < 8; ++t)
        #pragma unroll
        for (int j = 0; j < 4; ++j) acc[t][j] = 0.f;

    // prologue: stage slice 0 into buffer 0
    #pragma unroll
    for (int p = 0; p < 8; ++p)
        gl16(wsrc + (size_t)p * 8 * HH, wdst0 + p * 8 * BK);
    gl16(xsrc, xdst0);
    __syncthreads();

    const int NT = HH / BK; // 224
    for (int ts = 0; ts < NT; ++ts) {
        const int b = ts & 1;
        // stage next slice into the other buffer (async, overlaps compute)
        if (ts + 1 < NT) {
            const int k1 = (ts + 1) * BK;
            float* wd = (b ? wdst0 : wdst1);
            float* xd = (b ? xdst0 : xdst1);
            #pragma unroll
            for (int p = 0; p < 8; ++p)
                gl16(wsrc + (size_t)p * 8 * HH + k1, wd + p * 8 * BK);
            gl16(xsrc + k1, xd);
        }
        // compute slice ts from buffer b (all reads are in-order DS)
        const float* wl = sm.u.wbuf[b];
        const float* xl = &sm.xbuf[b][wv * 8 * BK];
        #pragma unroll
        for (int q = 0; q < 8; ++q) {
            const int wq = ((q ^ l7) << 2);       // swizzled k-chunk
            v4f w0 = *(const v4f*)&wl[(lane      ) * BK + wq];
            v4f w1 = *(const v4f*)&wl[(lane +  64) * BK + wq];
            v4f w2 = *(const v4f*)&wl[(lane + 128) * BK + wq];
            v4f w3 = *(const v4f*)&wl[(lane + 192) * BK + wq];
            v4f xv[8];
            #pragma unroll
            for (int t = 0; t < 8; ++t)           // uniform -> LDS broadcast
                xv[t] = *(const v4f*)&xl[t * BK + q * 4];
            #pragma unroll
            for (int t = 0; t < 8; ++t) {
                #pragma unroll
                for (int c = 0; c < 4; ++c) {     // k ascends per (t,expert)
                    float xs = xv[t][c];
                    acc[t][0] = fmaf(xs, w0[c], acc[t][0]);
                    acc[t][1] = fmaf(xs, w1[c], acc[t][1]);
                    acc[t][2] = fmaf(xs, w2[c], acc[t][2]);
                    acc[t][3] = fmaf(xs, w3[c], acc[t][3]);
                }
            }
        }
        __syncthreads();  // drains vmcnt (stage landed) + all waves done
    }

    // dump logits (union with wbuf: all w reads complete)
    #pragma unroll
    for (int t = 0; t < 8; ++t)
        #pragma unroll
        for (int j = 0; j < 4; ++j)
            sm.u.logits[wv * 8 + t][lane + 64 * j] = acc[t][j];
    __syncthreads();

    // ---- routing: round-7 verbatim (ties -> higher index) ----
    for (int tt = wv; tt < BMT; tt += 4) {
        const int gt = bm + tt;
        float4 lg = *(const float4*)&sm.u.logits[tt][lane * 4];
        float lgv[4] = {lg.x, lg.y, lg.z, lg.w};
        float s[4], sc[4], m[4];
        #pragma unroll
        for (int j = 0; j < 4; ++j) {
            float e = (float)exp(-(double)lgv[j]);
            float u = __fadd_rn(1.0f, e);
            s[j] = __fdiv_rn(1.0f, u);
            sc[j] = __fadd_rn(s[j], sm.bias[lane * 4 + j]);
        }
        float a1 = fmaxf(sc[0], sc[1]), a2 = fminf(sc[0], sc[1]);
        if (sc[2] > a1) { a2 = a1; a1 = sc[2]; } else a2 = fmaxf(a2, sc[2]);
        if (sc[3] > a1) { a2 = a1; a1 = sc[3]; } else a2 = fmaxf(a2, sc[3]);
        #pragma unroll
        for (int off = 1; off <= 4; off <<= 1) {
            float b1 = __shfl_xor(a1, off);
            float b2 = __shfl_xor(a2, off);
            float m1 = fmaxf(a1, b1);
            float m2 = fmaxf(fminf(a1, b1), (a1 >= b1) ? a2 : b2);
            a1 = m1; a2 = m2;
        }
        float gsc = __fadd_rn(a1, a2);
        float gsv[8];
        #pragma unroll
        for (int g = 0; g < 8; ++g) gsv[g] = __shfl(gsc, g * 8);
        int gm = lane >> 3;
        int rank = 0;
        #pragma unroll
        for (int hh = 0; hh < 8; ++hh)
            rank += (gsv[hh] > gsv[gm]) || (gsv[hh] == gsv[gm] && hh > gm);
        bool selg = rank < 4;
        #pragma unroll
        for (int j = 0; j < 4; ++j) m[j] = selg ? sc[j] : 0.0f;

        float selw = 0.f; int seli = 0;
        #pragma unroll
        for (int k = 0; k < 8; ++k) {
            float bv = m[0]; int bj = 0;
            #pragma unroll
            for (int j = 1; j < 4; ++j)
                if (m[j] >= bv) { bv = m[j]; bj = j; }
            float v = bv; int ii = lane * 4 + bj;
            #pragma unroll
            for (int off = 1; off < 64; off <<= 1) {
                float ov = __shfl_xor(v, off);
                int oi = __shfl_xor(ii, off);
                if (ov > v || (ov == v && oi > ii)) { v = ov; ii = oi; }
            }
            int oj = ii & 3, ol = ii >> 2;
            float cand = (oj == 0) ? s[0] : (oj == 1) ? s[1]
                       : (oj == 2) ? s[2] : s[3];
            float wgt = __shfl(cand, ol);
            if (lane == k) { seli = ii; selw = wgt; }
            if (lane == ol) {
                if (oj == 0) m[0] = -1e30f;
                else if (oj == 1) m[1] = -1e30f;
                else if (oj == 2) m[2] = -1e30f;
                else m[3] = -1e30f;
            }
        }
        float wk[8];
        #pragma unroll
        for (int k = 0; k < 8; ++k) wk[k] = __shfl(selw, k);
        float denom = __fadd_rn(
            __fadd_rn(__fadd_rn(wk[0], wk[1]), __fadd_rn(wk[2], wk[3])),
            __fadd_rn(__fadd_rn(wk[4], wk[5]), __fadd_rn(wk[6], wk[7])));
        denom = __fadd_rn(denom, 1e-20f);
        if (lane < 8) {
            out[(size_t)gt * 8 + lane] = (float)seli;
            out[(size_t)T * 8 + (size_t)gt * 8 + lane] =
                __fmul_rn(__fdiv_rn(selw, denom), 2.5f);
        }
    }
}

extern "C" void kernel_launch(void* const* d_in, const int* in_sizes, int n_in,
                              void* d_out, int out_size, void* d_ws, size_t ws_size,
                              hipStream_t stream) {
    const float* x    = (const float*)d_in[0];
    const float* w    = (const float*)d_in[1];
    const float* bias = (const float*)d_in[2];
    float* out = (float*)d_out;
    const int T = in_sizes[0] / HH; // 16384
    moe_gate<<<T / BMT, NTH, 0, stream>>>(x, w, bias, out, T);
}